// Round 2
// baseline (487.644 us; speedup 1.0000x reference)
//
#include <hip/hip_runtime.h>

#define T_STEPS 8

// IF-neuron recurrence over T=8 steps, independent per spatial element.
// Memory-bound: 9 float4 loads + 9 float4 stores per thread, coalesced.
//
// NUMERICS: the harness compares against a float64 numpy ground truth
// ("ref=np") with threshold 2e-2 on a {-1,0,+1}-valued output. A float32
// trajectory flips O(1e3) spikes vs the float64 trajectory (chaotic at the
// threshold), so we must integrate the recurrence in double precision.
// A float64 trajectory only flips if mem lands within ~1e-15 of the
// threshold (expected flips over 75M elements ~ 1e-6), so it is robust.
// Divisions by (t+1) use true IEEE double division (compiler folds the
// exact pow2 cases 1,2,4,8 into multiplies; 3,5,6,7 stay correctly-rounded
// divides). No fast-math.

__global__ __launch_bounds__(256) void if_diff_kernel(
    const float4* __restrict__ x,
    const float* __restrict__ thresh_p,
    float4* __restrict__ out,
    int n4)
{
    int i = blockIdx.x * blockDim.x + threadIdx.x;
    if (i >= n4) return;

    const double th = (double)thresh_p[0];

    // x0 = first temporal slice
    float4 x0v = x[i];
    double x0[4] = {(double)x0v.x, (double)x0v.y, (double)x0v.z, (double)x0v.w};

    // output slice 0 is all zeros (harness poisons d_out, so write it)
    out[i] = make_float4(0.f, 0.f, 0.f, 0.f);

    double mem[4], ein[4], eout[4];
    #pragma unroll
    for (int c = 0; c < 4; ++c) { mem[c] = 0.5 * th; ein[c] = 0.0; eout[c] = 0.0; }

    #pragma unroll
    for (int t = 0; t < T_STEPS; ++t) {
        const double div_t = (double)(t + 1);  // exact small integer
        float4 xv = x[(size_t)(t + 1) * (size_t)n4 + (size_t)i];
        double xt[4] = {(double)xv.x, (double)xv.y, (double)xv.z, (double)xv.w};
        float sp[4];
        #pragma unroll
        for (int c = 0; c < 4; ++c) {
            // mem = mem + xt + exp_in - exp_out   (reference assoc order)
            double m = ((mem[c] + xt[c]) + ein[c]) - eout[c];
            // spike = zif(m - th)*th - zif(-m)*th ; zif(u) = (u >= 0)
            double s = ((m - th) >= 0.0 ? th : 0.0) - ((-m) >= 0.0 ? th : 0.0);
            m = m - s;
            ein[c]  = ein[c]  + (xt[c] - x0[c]) / div_t;
            eout[c] = eout[c] + s / div_t;
            mem[c] = m;
            sp[c] = (float)s;
        }
        out[(size_t)(t + 1) * (size_t)n4 + (size_t)i] =
            make_float4(sp[0], sp[1], sp[2], sp[3]);
    }
}

extern "C" void kernel_launch(void* const* d_in, const int* in_sizes, int n_in,
                              void* d_out, int out_size, void* d_ws, size_t ws_size,
                              hipStream_t stream) {
    const float* x      = (const float*)d_in[0];
    const float* thresh = (const float*)d_in[1];
    float* out          = (float*)d_out;

    const int N  = in_sizes[0] / (T_STEPS + 1);  // elements per temporal slice
    const int n4 = N / 4;                        // float4 groups per slice

    const int block = 256;
    const int grid  = (n4 + block - 1) / block;
    if_diff_kernel<<<grid, block, 0, stream>>>(
        (const float4*)x, thresh, (float4*)out, n4);
}